// Round 6
// baseline (134.808 us; speedup 1.0000x reference)
//
#include <hip/hip_runtime.h>
#include <math.h>

#define B_ 4
#define S_ 2048
#define D_ 512
#define H_ 8
#define DH_ 64
#define BH_ (B_*H_)
#define SCALE 0.1803368801111243f   // log2(e)/sqrt(64)

typedef __attribute__((ext_vector_type(4)))  float f32x4;
typedef __attribute__((ext_vector_type(16))) float f32x16;
typedef __attribute__((ext_vector_type(8)))  short bf16x8;
typedef __attribute__((ext_vector_type(4)))  uint  u32x4;

__device__ inline uint rnepk(float a, float b) {
    uint ua = __builtin_bit_cast(uint, a), ub = __builtin_bit_cast(uint, b);
    ua += 0x7FFFu + ((ua >> 16) & 1u);
    ub += 0x7FFFu + ((ub >> 16) & 1u);
    return (ua >> 16) | (ub & 0xFFFF0000u);
}
__device__ inline uint truncpk(float lo, float hi) {   // 1 v_perm_b32
    return __builtin_amdgcn_perm(__builtin_bit_cast(uint, hi),
                                 __builtin_bit_cast(uint, lo), 0x07060302u);
}
__device__ inline f32x16 zero16() {
    f32x16 z;
    #pragma unroll
    for (int i = 0; i < 16; ++i) z[i] = 0.f;
    return z;
}
__device__ inline bf16x8 pack8(f32x4 a, f32x4 c) {
    u32x4 u;
    u.x = rnepk(a[0], a[1]); u.y = rnepk(a[2], a[3]);
    u.z = rnepk(c[0], c[1]); u.w = rnepk(c[2], c[3]);
    return __builtin_bit_cast(bf16x8, u);
}

// (a,b) -> a' = [a.lo | b.from-partner], b' = [a.from-partner | b.hi]:
// a_new[l<32]=a[l], a_new[l>=32]=b[l-32]; b_new[l<32]=a[l+32], b_new[l>=32]=b[l]
#if __has_builtin(__builtin_amdgcn_permlane32_swap)
__device__ inline void lane32swap(uint& a, uint& b) {
    typedef __attribute__((ext_vector_type(2))) uint u32x2;
    u32x2 r = __builtin_amdgcn_permlane32_swap(a, b, false, false);
    a = r.x; b = r.y;
}
#else
__device__ inline void lane32swap(uint& a, uint& b) {
    const int l5 = (threadIdx.x & 63) >> 5;
    uint send = l5 ? a : b;
    uint recv = __shfl_xor(send, 32);
    uint an = l5 ? recv : a;
    uint bn = l5 ? b : recv;
    a = an; b = bn;
}
#endif

// ---------------------------------------------------------------------------
// Kernel 1: QKV projection, 32x32x16 MFMA, ZERO barriers. grid (BH_, S_/128),
// block 256. Fragments loaded directly from global (x/W are L1/L2-resident),
// packed fp32->bf16 in-register. Per-wave LDS bounce only for coalesced
// stores (wave-synchronous, no __syncthreads anywhere).
// ---------------------------------------------------------------------------
__global__ __launch_bounds__(256, 2)
void qkv_mfma(const float* __restrict__ x,
              const float* __restrict__ Wq, const float* __restrict__ bq,
              const float* __restrict__ Wk, const float* __restrict__ bk,
              const float* __restrict__ Wv, const float* __restrict__ bv,
              ushort* __restrict__ Qb, ushort* __restrict__ Kb,
              ushort* __restrict__ Vtg)
{
    const int bh = blockIdx.x, b = bh >> 3, h = bh & 7;
    const int s0 = blockIdx.y * 128;
    const int tid = threadIdx.x;
    const int w = tid >> 6, lane = tid & 63, l31 = lane & 31, l5 = lane >> 5;

    __shared__ __align__(16) ushort bnc[4][2560];    // per-wave bounce, 20 KB
    ushort* mybnc = &bnc[w][0];

    const int srow = w * 32 + l31;                   // this lane's s-row
    // ---- x fragments straight from global ----
    const float* xr = x + ((size_t)(b * S_ + s0 + srow)) * D_ + h * DH_;
    bf16x8 xf[4];
    #pragma unroll
    for (int st = 0; st < 4; ++st) {
        f32x4 a = *(const f32x4*)(xr + st * 16 + l5 * 8);
        f32x4 c = *(const f32x4*)(xr + st * 16 + l5 * 8 + 4);
        xf[st] = pack8(a, c);
    }

    const float* Wm[3] = {Wq, Wk, Wv};
    #pragma unroll
    for (int mat = 0; mat < 3; ++mat) {
        // ---- W fragments straight from global: rows e = et*32 + l31 ----
        bf16x8 wf[2][4];
        #pragma unroll
        for (int et = 0; et < 2; ++et) {
            const float* wr = Wm[mat] + h * DH_ * DH_ + (et * 32 + l31) * DH_;
            #pragma unroll
            for (int st = 0; st < 4; ++st) {
                f32x4 a = *(const f32x4*)(wr + st * 16 + l5 * 8);
                f32x4 c = *(const f32x4*)(wr + st * 16 + l5 * 8 + 4);
                wf[et][st] = pack8(a, c);
            }
        }

        if (mat < 2) {
            // Q/K: C[e][s] — A=W, B=x
            const float* bias = mat ? bk : bq;
            #pragma unroll
            for (int et = 0; et < 2; ++et) {
                f32x16 acc = zero16();
                #pragma unroll
                for (int st = 0; st < 4; ++st)
                    acc = __builtin_amdgcn_mfma_f32_32x32x16_bf16(wf[et][st], xf[st], acc, 0, 0, 0);
                #pragma unroll
                for (int rg = 0; rg < 4; ++rg) {
                    float4 b4 = *(const float4*)(bias + h * DH_ + et * 32 + rg * 8 + l5 * 4);
                    float v0 = acc[rg * 4 + 0] + b4.x;
                    float v1 = acc[rg * 4 + 1] + b4.y;
                    float v2 = acc[rg * 4 + 2] + b4.z;
                    float v3 = acc[rg * 4 + 3] + b4.w;
                    if (mat == 0) { v0 *= SCALE; v1 *= SCALE; v2 *= SCALE; v3 *= SCALE; }
                    uint2 pk;
                    pk.x = rnepk(v0, v1); pk.y = rnepk(v2, v3);
                    *(uint2*)(mybnc + l31 * 72 + et * 32 + rg * 8 + l5 * 4) = pk;   // [s][e]
                }
            }
            ushort* Og = mat ? Kb : Qb;
            #pragma unroll
            for (int i = 0; i < 4; ++i) {            // 32 s-rows x 8 chunks, coalesced
                const int slot = lane + 64 * i;
                const int r = slot >> 3, c = slot & 7;
                uint4 v = *(const uint4*)(mybnc + r * 72 + c * 8);
                *(uint4*)(Og + ((size_t)(bh * S_ + s0 + w * 32 + r)) * DH_ + c * 8) = v;
            }
        } else {
            // V: C[s][e] — A=x, B=Wv (same fragments, swapped) -> Vt[e][s]
            #pragma unroll
            for (int et = 0; et < 2; ++et) {
                f32x16 acc = zero16();
                #pragma unroll
                for (int st = 0; st < 4; ++st)
                    acc = __builtin_amdgcn_mfma_f32_32x32x16_bf16(xf[st], wf[et][st], acc, 0, 0, 0);
                const float bb = bv[h * DH_ + et * 32 + l31];
                #pragma unroll
                for (int rg = 0; rg < 4; ++rg) {
                    uint2 pk;
                    pk.x = rnepk(acc[rg * 4 + 0] + bb, acc[rg * 4 + 1] + bb);
                    pk.y = rnepk(acc[rg * 4 + 2] + bb, acc[rg * 4 + 3] + bb);
                    *(uint2*)(mybnc + (et * 32 + l31) * 40 + rg * 8 + l5 * 4) = pk; // [e][s]
                }
            }
            #pragma unroll
            for (int i = 0; i < 4; ++i) {            // 64 e-rows x 4 chunks
                const int slot = lane + 64 * i;
                const int r = slot >> 2, c = slot & 3;
                uint4 v = *(const uint4*)(mybnc + r * 40 + c * 8);
                *(uint4*)(Vtg + ((size_t)(bh * DH_ + r)) * S_ + s0 + w * 32 + c * 8) = v;
            }
        }
    }
}

// ---------------------------------------------------------------------------
// Kernel 2: flash attention, 32x32x16 MFMA, 32 q/wave, S^T orientation.
// grid 512 (2 blocks/CU, 8 waves/CU). P NEVER touches LDS: the C->B-frag
// transform is the (lane, lane^32) quad exchange done with permlane32_swap
// (VALU pipe). K/V double-buffered (9KB x2) -> ONE barrier per kt.
// Per-wave-kt LDS: 16 b128 reads + 4 b128 writes (was 28 KB in R5).
// ---------------------------------------------------------------------------
__global__ __launch_bounds__(256, 2)
void flash_mfma(const ushort* __restrict__ Qb, const ushort* __restrict__ Kb,
                const ushort* __restrict__ Vtg, float* __restrict__ out)
{
    const int blk = blockIdx.x;
    const int bh = blk & 31, qblk = blk >> 5;
    const int b = bh >> 3, h = bh & 7;
    const int tid = threadIdx.x;
    const int w = tid >> 6, lane = tid & 63, l31 = lane & 31, l5 = lane >> 5;

    // Ks[buf] at buf*4096, Vs[buf] at 8192+buf*4096 (ushorts). Epilogue
    // overlays everything (4 waves x 32x68 fp32 = 34816 B = whole array).
    __shared__ __align__(16) ushort lds_u[17408];

    // ---- Q B-frags (held all kernel): q = q0 + l31 ----
    const int q0 = qblk * 128 + w * 32;
    bf16x8 qf[4];
    #pragma unroll
    for (int st = 0; st < 4; ++st)
        qf[st] = *(const bf16x8*)(Qb + ((size_t)(bh * S_ + q0 + l31)) * DH_
                                  + st * 16 + l5 * 8);

    f32x16 O[2];                       // O^T [dht]: lane col = q = l31
    O[0] = zero16(); O[1] = zero16();
    float lsum = 0.f;

    const ushort* kg = Kb + (size_t)bh * S_ * DH_;
    const ushort* vg = Vtg + (size_t)bh * DH_ * S_;
    const int sr0 = tid >> 3, sc = tid & 7, sr1 = sr0 + 32;
    const int swz0 = (sc ^ (sr0 & 7)) * 8, swz1 = (sc ^ (sr1 & 7)) * 8;

    // ---- prologue: stage kt=0 into buffer 0 ----
    {
        uint4 k0 = *(const uint4*)(kg + (size_t)sr0 * DH_ + sc * 8);
        uint4 k1 = *(const uint4*)(kg + (size_t)sr1 * DH_ + sc * 8);
        uint4 v0 = *(const uint4*)(vg + (size_t)sr0 * S_ + sc * 8);
        uint4 v1 = *(const uint4*)(vg + (size_t)sr1 * S_ + sc * 8);
        *(uint4*)(lds_u + sr0 * 64 + swz0) = k0;
        *(uint4*)(lds_u + sr1 * 64 + swz1) = k1;
        *(uint4*)(lds_u + 8192 + sr0 * 64 + swz0) = v0;
        *(uint4*)(lds_u + 8192 + sr1 * 64 + swz1) = v1;
    }

    for (int kt = 0; kt < 32; ++kt) {
        __syncthreads();   // buf[cur] writes visible; buf[nxt] reads (kt-1) done
        const int cur = kt & 1, nxt = cur ^ 1;
        uint4 kv0, kv1, vv0, vv1;
        if (kt < 31) {                        // prefetch kt+1 into registers
            const size_t ko = (size_t)(kt + 1) * 64 * DH_;
            const int vo = (kt + 1) * 64;
            kv0 = *(const uint4*)(kg + ko + (size_t)sr0 * DH_ + sc * 8);
            kv1 = *(const uint4*)(kg + ko + (size_t)sr1 * DH_ + sc * 8);
            vv0 = *(const uint4*)(vg + (size_t)sr0 * S_ + vo + sc * 8);
            vv1 = *(const uint4*)(vg + (size_t)sr1 * S_ + vo + sc * 8);
        }
        const ushort* ksb = lds_u + cur * 4096;
        const ushort* vsb = lds_u + 8192 + cur * 4096;

        // ---- S^T = K·Q^T, exp, pack, in-register quad exchange -> pf ----
        bf16x8 pf[4];                          // PV B-frags, built per g
        #pragma unroll
        for (int g = 0; g < 2; ++g) {
            const int key = g * 32 + l31;
            bf16x8 kf[4];
            #pragma unroll
            for (int st = 0; st < 4; ++st)
                kf[st] = *(const bf16x8*)(ksb + key * 64 + (((st * 2 + l5) ^ (key & 7)) * 8));
            f32x16 sc_ = zero16();
            #pragma unroll
            for (int st = 0; st < 4; ++st)
                sc_ = __builtin_amdgcn_mfma_f32_32x32x16_bf16(kf[st], qf[st], sc_, 0, 0, 0);
            uint pr[8];                        // pr[2*rg+c]: keys 8rg+4l5+{2c,2c+1}
            #pragma unroll
            for (int rg = 0; rg < 4; ++rg) {
                float p0 = __builtin_amdgcn_exp2f(sc_[rg * 4 + 0]);
                float p1 = __builtin_amdgcn_exp2f(sc_[rg * 4 + 1]);
                float p2 = __builtin_amdgcn_exp2f(sc_[rg * 4 + 2]);
                float p3 = __builtin_amdgcn_exp2f(sc_[rg * 4 + 3]);
                lsum += (p0 + p1) + (p2 + p3);
                pr[2 * rg + 0] = truncpk(p0, p1);
                pr[2 * rg + 1] = truncpk(p2, p3);
            }
            // exchange: pair rg {2p, 2p+1} across (lane, lane^32)
            #pragma unroll
            for (int p = 0; p < 2; ++p) {
                lane32swap(pr[4 * p + 0], pr[4 * p + 2]);
                lane32swap(pr[4 * p + 1], pr[4 * p + 3]);
                u32x4 u; u.x = pr[4 * p + 0]; u.y = pr[4 * p + 1];
                u.z = pr[4 * p + 2]; u.w = pr[4 * p + 3];
                pf[g * 2 + p] = __builtin_bit_cast(bf16x8, u);
            }
        }

        // ---- PV: O^T[dht] += Vt·P^T ----
        #pragma unroll
        for (int dht = 0; dht < 2; ++dht) {
            const int dh = dht * 32 + l31;
            bf16x8 vf[4];
            #pragma unroll
            for (int st = 0; st < 4; ++st)
                vf[st] = *(const bf16x8*)(vsb + dh * 64 + (((st * 2 + l5) ^ (dh & 7)) * 8));
            #pragma unroll
            for (int st = 0; st < 4; ++st)
                O[dht] = __builtin_amdgcn_mfma_f32_32x32x16_bf16(vf[st], pf[st], O[dht], 0, 0, 0);
        }

        // ---- write prefetched tile kt+1 into the other buffer ----
        if (kt < 31) {
            ushort* kn = lds_u + nxt * 4096;
            ushort* vn = lds_u + 8192 + nxt * 4096;
            *(uint4*)(kn + sr0 * 64 + swz0) = kv0;
            *(uint4*)(kn + sr1 * 64 + swz1) = kv1;
            *(uint4*)(vn + sr0 * 64 + swz0) = vv0;
            *(uint4*)(vn + sr1 * 64 + swz1) = vv1;
        }
    }

    // ---- finalize ----
    lsum += __shfl_xor(lsum, 32);
    const float linv = 1.0f / lsum;
    #pragma unroll
    for (int dht = 0; dht < 2; ++dht)
        #pragma unroll
        for (int i = 0; i < 16; ++i) O[dht][i] *= linv;

    __syncthreads();                          // overlay LDS with O bounce
    float* ob = (float*)lds_u + w * (32 * 68);   // per-wave [32 q][68] fp32
    #pragma unroll
    for (int dht = 0; dht < 2; ++dht)
        #pragma unroll
        for (int rg = 0; rg < 4; ++rg) {
            f32x4 v4;
            v4[0] = O[dht][rg * 4 + 0];
            v4[1] = O[dht][rg * 4 + 1];
            v4[2] = O[dht][rg * 4 + 2];
            v4[3] = O[dht][rg * 4 + 3];
            *(f32x4*)(ob + l31 * 68 + dht * 32 + rg * 8 + l5 * 4) = v4;
        }
    #pragma unroll
    for (int i = 0; i < 8; ++i) {             // 32 rows x 16 chunks of 16 B
        const int slot = lane + 64 * i;
        const int r = slot >> 4, c = slot & 15;
        f32x4 v = *(const f32x4*)(ob + r * 68 + c * 4);
        *(f32x4*)(out + ((size_t)(b * S_ + q0 + r)) * D_ + h * DH_ + c * 4) = v;
    }
}

extern "C" void kernel_launch(void* const* d_in, const int* in_sizes, int n_in,
                              void* d_out, int out_size, void* d_ws, size_t ws_size,
                              hipStream_t stream) {
    const float* x  = (const float*)d_in[0];
    const float* Wq = (const float*)d_in[1];
    const float* bq = (const float*)d_in[2];
    const float* Wk = (const float*)d_in[3];
    const float* bk = (const float*)d_in[4];
    const float* Wv = (const float*)d_in[5];
    const float* bv = (const float*)d_in[6];
    float* outp = (float*)d_out;

    ushort* Qb  = (ushort*)d_ws;                       // [BH][S][DH] bf16, 8 MB
    ushort* Kb  = Qb + (size_t)BH_ * S_ * DH_;         // 8 MB
    ushort* Vtg = Kb + (size_t)BH_ * S_ * DH_;         // [BH][DH][S] bf16, 8 MB

    qkv_mfma<<<dim3(BH_, S_ / 128), 256, 0, stream>>>(x, Wq, bq, Wk, bk, Wv, bv,
                                                      Qb, Kb, Vtg);
    flash_mfma<<<dim3(32 * 16), 256, 0, stream>>>(Qb, Kb, Vtg, outp);
}